// Round 7
// baseline (661.537 us; speedup 1.0000x reference)
//
#include <hip/hip_runtime.h>

typedef __bf16 bf16x8 __attribute__((ext_vector_type(8)));
typedef __bf16 bf16x4 __attribute__((ext_vector_type(4)));
typedef float  f32x4  __attribute__((ext_vector_type(4)));

#define MFMA16(A, B, C) __builtin_amdgcn_mfma_f32_16x16x32_bf16(A, B, C, 0, 0, 0)
#define AS1 __attribute__((address_space(1)))
#define AS3 __attribute__((address_space(3)))

#if __has_builtin(__builtin_amdgcn_exp2f)
#define EXP2F(x) __builtin_amdgcn_exp2f(x)
#else
#define EXP2F(x) exp2f(x)
#endif

// ---------------- elementwise fp32 -> bf16 ----------------
__global__ __launch_bounds__(256) void convert_f32_bf16(const float* __restrict__ src,
                                                        __bf16* __restrict__ dst) {
    size_t i = ((size_t)blockIdx.x * 256 + threadIdx.x) * 4;
    float4 v = *(const float4*)(src + i);
    bf16x4 o;
    o.x = (__bf16)v.x; o.y = (__bf16)v.y; o.z = (__bf16)v.z; o.w = (__bf16)v.w;
    *(bf16x4*)(dst + i) = o;
}

// ---------------- 2048x2048 fp32 -> bf16 transpose (W -> W^T rows=[n][k]) ----------------
__global__ __launch_bounds__(256) void transpose_conv(const float* __restrict__ src,
                                                      __bf16* __restrict__ dst) {
    __shared__ float t[32][33];
    int x0 = blockIdx.x * 32, y0 = blockIdx.y * 32;
    int tx = threadIdx.x, ty = threadIdx.y;   // 32x8
    for (int r = 0; r < 4; ++r)
        t[ty + 8 * r][tx] = src[(size_t)(y0 + ty + 8 * r) * 2048 + x0 + tx];
    __syncthreads();
    for (int r = 0; r < 4; ++r)
        dst[(size_t)(x0 + ty + 8 * r) * 2048 + y0 + tx] = (__bf16)t[tx][ty + 8 * r];
}

// ---------------- per-head V transpose: qkv[s][4096+h*128+d] -> vtb[h][d][s] ----------------
__global__ __launch_bounds__(256) void v_transpose(const __bf16* __restrict__ qkv,
                                                   __bf16* __restrict__ vtb) {
    __shared__ __bf16 t[32][33];
    int h = blockIdx.z;
    int s0 = blockIdx.x * 32, d0 = blockIdx.y * 32;
    int tx = threadIdx.x, ty = threadIdx.y;   // 32x8
    for (int r = 0; r < 4; ++r)
        t[ty + 8 * r][tx] = qkv[(size_t)(s0 + ty + 8 * r) * 6144 + 4096 + h * 128 + d0 + tx];
    __syncthreads();
    for (int r = 0; r < 4; ++r)
        vtb[(size_t)h * 128 * 4096 + (size_t)(d0 + ty + 8 * r) * 4096 + s0 + tx] = t[tx][ty + 8 * r];
}

// ---------------- fused RMSNorm + RoPE; head-major Q (pre-scaled by log2e/sqrt(128)) and K ----------------
__global__ __launch_bounds__(64) void rmsrope(const __bf16* __restrict__ qkv,
                                              const float* __restrict__ qw,
                                              const float* __restrict__ kw,
                                              const int* __restrict__ pos_ids,
                                              __bf16* __restrict__ qhb,
                                              __bf16* __restrict__ khb) {
    int s = blockIdx.x;
    int slot = blockIdx.y;              // 0..31: 0-15 = q heads, 16-31 = k heads
    int lane = threadIdx.x;             // 0..63, handles dim pair (2*lane, 2*lane+1)
    bool isQ = slot < 16;
    int h = slot & 15;
    size_t base = (size_t)s * 6144 + (isQ ? 0 : 2048) + h * 128 + lane * 2;
    float x0 = (float)qkv[base], x1 = (float)qkv[base + 1];
    float ss = x0 * x0 + x1 * x1;
    for (int m = 1; m < 64; m <<= 1) ss += __shfl_xor(ss, m);
    float rr = rsqrtf(ss * (1.0f / 128.0f) + 1e-6f);
    const float* wp = isQ ? qw : kw;
    float n0 = x0 * rr * wp[lane * 2], n1 = x1 * rr * wp[lane * 2 + 1];
    float freq = powf(10000.0f, -(float)lane * (1.0f / 64.0f));
    float ang = (float)pos_ids[s] * freq;
    float sn, cs;
    sincosf(ang, &sn, &cs);
    float o0 = n0 * cs - n1 * sn;
    float o1 = n0 * sn + n1 * cs;
    // fold (1/sqrt(128)) * log2(e) into Q so scores are in exp2 domain
    if (isQ) { o0 *= 0.12751744416196178f; o1 *= 0.12751744416196178f; }
    __bf16* dst = (isQ ? qhb : khb) + (size_t)h * 4096 * 128 + (size_t)s * 128 + lane * 2;
    dst[0] = (__bf16)o0; dst[1] = (__bf16)o1;
}

// ---------------- generic bf16 MFMA GEMM: C[M,N] = A[M,K] * Bt[N,K]^T ----------------
// 128x128 tile, 4 waves, 4x4 16x16x32 MFMA per wave. global_load_lds width-16 staging (m97).
// R7: GEMM T1 swizzle reverted (R6 non-flash time grew ~24us; inputs are L3-fit so the
// swizzle can only cost — m160; restores R0 GEMM exactly to isolate the flash change).
template <bool F32OUT>
__global__ __launch_bounds__(256) void gemm_bt(const __bf16* __restrict__ A, int lda,
                                               const __bf16* __restrict__ Bt, int ldb,
                                               void* __restrict__ Cout, int ldc, int K) {
    __shared__ __bf16 as[128][32];   // unpadded: required by global_load_lds contiguity
    __shared__ __bf16 bs[128][32];
    const int m0 = blockIdx.x * 128, n0 = blockIdx.y * 128;
    const int t = threadIdx.x;
    const int lane = t & 63, w = t >> 6;
    const int wm = (w >> 1) * 64, wn = (w & 1) * 64;
    const int ln = lane & 15, quad = lane >> 4;
    auto as3 = (AS3 uint32_t*)as;
    auto bs3 = (AS3 uint32_t*)bs;
    f32x4 acc[4][4] = {};
    for (int k0 = 0; k0 < K; k0 += 32) {
        for (int c = 0; c < 2; ++c) {
            int g = c * 256 + t;               // chunk id: 512 chunks of 16B per tile
            int row = g >> 2, kc = g & 3;
            const __bf16* ga = &A[(size_t)(m0 + row) * lda + k0 + kc * 8];
            const __bf16* gb = &Bt[(size_t)(n0 + row) * ldb + k0 + kc * 8];
            __builtin_amdgcn_global_load_lds((const AS1 uint32_t*)ga,
                                             as3 + c * 1024 + w * 256, 16, 0, 0);
            __builtin_amdgcn_global_load_lds((const AS1 uint32_t*)gb,
                                             bs3 + c * 1024 + w * 256, 16, 0, 0);
        }
        __syncthreads();
        bf16x8 af[4], bfr[4];
        for (int i = 0; i < 4; ++i) af[i] = *(const bf16x8*)&as[wm + i * 16 + ln][quad * 8];
        for (int j = 0; j < 4; ++j) bfr[j] = *(const bf16x8*)&bs[wn + j * 16 + ln][quad * 8];
        for (int i = 0; i < 4; ++i)
            for (int j = 0; j < 4; ++j)
                acc[i][j] = MFMA16(af[i], bfr[j], acc[i][j]);
        __syncthreads();
    }
    // C/D layout: col = lane&15, row = quad*4 + r   [m89/m91 verified]
    for (int i = 0; i < 4; ++i)
        for (int j = 0; j < 4; ++j)
            for (int r = 0; r < 4; ++r) {
                int row = m0 + wm + i * 16 + quad * 4 + r;
                int col = n0 + wn + j * 16 + ln;
                if (F32OUT) ((float*)Cout)[(size_t)row * ldc + col] = acc[i][j][r];
                else        ((__bf16*)Cout)[(size_t)row * ldc + col] = (__bf16)acc[i][j][r];
            }
}

// ---------------- flash attention, fixed-max softmax, BM=128 ----------------
// R7 = R6 compute (proven) with staging rebuilt:
//  - global_load_lds (width 16) K/V staging: data never transits VGPRs -> immune to the
//    R1-R5 reg-prefetch scratch pathology AND removes the staging VALU cost (m97 mechanism).
//  - double-buffered K/V + single __syncthreads per iter (T3 minimum 2-phase): next tile's
//    loads issued BEFORE compute; compiler's pre-barrier vmcnt(0) drain lands after compute.
//  - rule-21 both-sides swizzle: gload_lds writes linearly, so the XOR involution
//    (chunk ^ (row&7)) is applied on the per-lane GLOBAL source address and again on the
//    LDS read side; per-thread source chunk is loop-invariant (kcc/vcc).
// ps/softmax/epilogue byte-identical to R6. LDS 81KB -> 1 block/CU (dbuf replaces
// inter-block overlap with intra-block overlap).
__global__ __launch_bounds__(256) void flash_attn(const __bf16* __restrict__ Q,
                                                  const __bf16* __restrict__ Kb,
                                                  const __bf16* __restrict__ Vt,
                                                  __bf16* __restrict__ ctx) {
    __shared__ __bf16 kbuf[2][64][128];   // keys x dim, phys chunk = logical ^ (row&7)
    __shared__ __bf16 vbuf[2][128][64];   // dim x keys, same involution
    __shared__ __bf16 ps[4][32][68];      // per-wave P; stride 34 words (unchanged)

    // T1: XCD-contiguous remap (verified R1-R6: FETCH 139MB -> 25MB)
    int bid = blockIdx.x + (int)gridDim.x * blockIdx.y;
    int swz = (bid & 7) * 64 + (bid >> 3);
    const int h  = swz >> 5;
    const int m0 = (swz & 31) * 128;

    const int t = threadIdx.x;
    const int lane = t & 63, w = t >> 6;
    const int ln = lane & 15, quad = lane >> 4;
    const __bf16* Qh = Q + (size_t)h * 4096 * 128;
    const __bf16* Kh = Kb + (size_t)h * 4096 * 128;
    const __bf16* Vh = Vt + (size_t)h * 128 * 4096;

    // per-thread swizzled source chunks (loop-invariant)
    const int kcc = (t & 15) ^ ((t >> 4) & 7);   // K/Q: 16 chunks/row of 16B
    const int vcc = (t & 7) ^ ((t >> 3) & 7);    // V: 8 chunks/row of 16B
    auto kb3 = (AS3 uint32_t*)&kbuf[0][0][0];
    auto vb3 = (AS3 uint32_t*)&vbuf[0][0][0];
    const char* kbase = (const char*)&kbuf[0][0][0];
    const char* vbase = (const char*)&vbuf[0][0][0];

    // ---- stage Q through kbuf[0] (swizzled, regular stores), keep A-frags in registers ----
    bf16x8 qf[2][4];
    for (int half = 0; half < 2; ++half) {
        for (int i = 0; i < 4; ++i) {
            int row = (t >> 4) + i * 16;
            // phys slot (t&15) holds logical chunk kcc = (t&15)^(row&7)
            *(uint4*)&kbuf[0][row][(t & 15) * 8] =
                *(const uint4*)&Qh[(size_t)(m0 + half * 64 + row) * 128 + kcc * 8];
        }
        __syncthreads();
        int r = w * 16 + ln;
        for (int kk = 0; kk < 4; ++kk)
            qf[half][kk] = *(const bf16x8*)(kbase + r * 256 + ((((kk * 4 + quad) ^ (ln & 7)) << 4)));
        __syncthreads();
    }

    // ---- 2-phase pipeline: STAGE issues gload_lds; one barrier per iter ----
    // STAGE(tile -> buf): K 64x128 (4 calls) + V^T 128x64 (4 calls), 16B/lane each
#define STAGE_KV(buf, tile)                                                          \
    for (int i = 0; i < 4; ++i) {                                                    \
        int krow = (t >> 4) + i * 16;                                                \
        __builtin_amdgcn_global_load_lds(                                            \
            (const AS1 uint32_t*)&Kh[(size_t)((tile) * 64 + krow) * 128 + kcc * 8],  \
            kb3 + (buf) * 4096 + (w * 64 + i * 256) * 4, 16, 0, 0);                  \
        int vrow = (t >> 3) + i * 32;                                                \
        __builtin_amdgcn_global_load_lds(                                            \
            (const AS1 uint32_t*)&Vh[(size_t)vrow * 4096 + (tile) * 64 + vcc * 8],   \
            vb3 + (buf) * 4096 + (w * 64 + i * 256) * 4, 16, 0, 0);                  \
    }

    STAGE_KV(0, 0)
    __syncthreads();                  // drains tile-0 loads (compiler vmcnt before barrier)

    f32x4 oacc[2][8] = {};
    float rs[2][4] = {};              // per-lane partial sum of p (no rescale ever needed)
    int cur = 0;

    for (int kb = 0; kb < 64; ++kb) {
        if (kb + 1 < 64) { STAGE_KV(cur ^ 1, kb + 1) }   // async: lands under compute below

        const char* ksb = kbase + cur * 16384;
        const char* vsb = vbase + cur * 16384;

        // S~ = Q*K^T - 16.5 (bias via MFMA C-init); each kf frag reused for both row-tiles
        f32x4 sacc[2][4];
        const f32x4 mC = {-16.5f, -16.5f, -16.5f, -16.5f};
        for (int i = 0; i < 2; ++i)
            for (int j = 0; j < 4; ++j) sacc[i][j] = mC;
        for (int j = 0; j < 4; ++j)
            for (int kk = 0; kk < 4; ++kk) {
                bf16x8 kf = *(const bf16x8*)(ksb + (j * 16 + ln) * 256 +
                                             (((kk * 4 + quad) ^ (ln & 7)) << 4));
                sacc[0][j] = MFMA16(qf[0][kk], kf, sacc[0][j]);
                sacc[1][j] = MFMA16(qf[1][kk], kf, sacc[1][j]);
            }

        // p = exp2(s~); accumulate per-lane partial l; C-layout -> LDS (wave-private, no barrier)
        for (int i = 0; i < 2; ++i)
            for (int j = 0; j < 4; ++j)
                for (int r = 0; r < 4; ++r) {
                    float p = EXP2F(sacc[i][j][r]);
                    rs[i][r] += p;
                    ps[w][i * 16 + quad * 4 + r][j * 16 + ln] = (__bf16)p;
                }

        // O += P*V; each vf frag reused for both row-tiles
        bf16x8 pf[2][2];
        for (int i = 0; i < 2; ++i)
            for (int kk = 0; kk < 2; ++kk)
                pf[i][kk] = *(const bf16x8*)&ps[w][i * 16 + ln][kk * 32 + quad * 8];
        for (int t8 = 0; t8 < 8; ++t8)
            for (int kk = 0; kk < 2; ++kk) {
                bf16x8 vf = *(const bf16x8*)(vsb + (t8 * 16 + ln) * 128 +
                                             (((kk * 4 + quad) ^ (ln & 7)) << 4));
                oacc[0][t8] = MFMA16(pf[0][kk], vf, oacc[0][t8]);
                oacc[1][t8] = MFMA16(pf[1][kk], vf, oacc[1][t8]);
            }
        __syncthreads();              // everyone done reading buf[cur] AND next tile landed
        cur ^= 1;
    }
#undef STAGE_KV

    // reduce l across the 16 lanes of each quad-row, once
    float inv[2][4];
    for (int i = 0; i < 2; ++i)
        for (int r = 0; r < 4; ++r) {
            float s = rs[i][r];
            for (int msk = 1; msk < 16; msk <<= 1) s += __shfl_xor(s, msk);
            inv[i][r] = 1.0f / s;
        }
    for (int i = 0; i < 2; ++i)
        for (int t8 = 0; t8 < 8; ++t8)
            for (int r = 0; r < 4; ++r) {
                int row = m0 + i * 64 + w * 16 + quad * 4 + r;
                int col = h * 128 + t8 * 16 + ln;
                ctx[(size_t)row * 2048 + col] = (__bf16)(oacc[i][t8][r] * inv[i][r]);
            }
}

// ---------------- launch ----------------
extern "C" void kernel_launch(void* const* d_in, const int* in_sizes, int n_in,
                              void* d_out, int out_size, void* d_ws, size_t ws_size,
                              hipStream_t stream) {
    const float* hs  = (const float*)d_in[0];
    const int*   pos = (const int*)d_in[1];
    const float* wq  = (const float*)d_in[2];
    const float* wk  = (const float*)d_in[3];
    const float* wv  = (const float*)d_in[4];
    const float* wo  = (const float*)d_in[5];
    const float* qw  = (const float*)d_in[6];
    const float* kw  = (const float*)d_in[7];

    char* ws = (char*)d_ws;
    const size_t MB = 1024 * 1024;
    __bf16* xb     = (__bf16*)(ws + 0);
    __bf16* wqkvtb = (__bf16*)(ws + 16 * MB);
    __bf16* qhb    = (__bf16*)(ws + 0);
    __bf16* khb    = (__bf16*)(ws + 16 * MB);
    __bf16* vtb    = (__bf16*)(ws + 32 * MB);
    __bf16* qkvb   = (__bf16*)(ws + 48 * MB);
    __bf16* ctxb   = (__bf16*)(ws + 48 * MB);
    __bf16* wotb   = (__bf16*)(ws + 96 * MB);

    dim3 tb(32, 8);
    convert_f32_bf16<<<8192, 256, 0, stream>>>(hs, xb);
    transpose_conv<<<dim3(64, 64), tb, 0, stream>>>(wq, wqkvtb);
    transpose_conv<<<dim3(64, 64), tb, 0, stream>>>(wk, wqkvtb + (size_t)2048 * 2048);
    transpose_conv<<<dim3(64, 64), tb, 0, stream>>>(wv, wqkvtb + (size_t)2 * 2048 * 2048);
    transpose_conv<<<dim3(64, 64), tb, 0, stream>>>(wo, wotb);

    // QKV projection: [4096,2048] x [2048,6144]
    gemm_bt<false><<<dim3(32, 48), 256, 0, stream>>>(xb, 2048, wqkvtb, 2048, qkvb, 6144, 2048);

    rmsrope<<<dim3(4096, 32), 64, 0, stream>>>(qkvb, qw, kw, pos, qhb, khb);
    v_transpose<<<dim3(128, 4, 16), tb, 0, stream>>>(qkvb, vtb);

    flash_attn<<<dim3(32, 16), 256, 0, stream>>>(qhb, khb, vtb, ctxb);

    // output projection: [4096,2048] x [2048,2048] -> fp32 out
    gemm_bt<true><<<dim3(32, 16), 256, 0, stream>>>(ctxb, 2048, wotb, 2048, d_out, 2048, 2048);
}

// Round 8
// 539.823 us; speedup vs baseline: 1.2255x; 1.2255x over previous
//
#include <hip/hip_runtime.h>

typedef __bf16 bf16x8 __attribute__((ext_vector_type(8)));
typedef __bf16 bf16x4 __attribute__((ext_vector_type(4)));
typedef float  f32x4  __attribute__((ext_vector_type(4)));

#define MFMA16(A, B, C) __builtin_amdgcn_mfma_f32_16x16x32_bf16(A, B, C, 0, 0, 0)
#define AS1 __attribute__((address_space(1)))
#define AS3 __attribute__((address_space(3)))

#if __has_builtin(__builtin_amdgcn_exp2f)
#define EXP2F(x) __builtin_amdgcn_exp2f(x)
#else
#define EXP2F(x) exp2f(x)
#endif

// ---------------- elementwise fp32 -> bf16 ----------------
__global__ __launch_bounds__(256) void convert_f32_bf16(const float* __restrict__ src,
                                                        __bf16* __restrict__ dst) {
    size_t i = ((size_t)blockIdx.x * 256 + threadIdx.x) * 4;
    float4 v = *(const float4*)(src + i);
    bf16x4 o;
    o.x = (__bf16)v.x; o.y = (__bf16)v.y; o.z = (__bf16)v.z; o.w = (__bf16)v.w;
    *(bf16x4*)(dst + i) = o;
}

// ---------------- 2048x2048 fp32 -> bf16 transpose (W -> W^T rows=[n][k]) ----------------
__global__ __launch_bounds__(256) void transpose_conv(const float* __restrict__ src,
                                                      __bf16* __restrict__ dst) {
    __shared__ float t[32][33];
    int x0 = blockIdx.x * 32, y0 = blockIdx.y * 32;
    int tx = threadIdx.x, ty = threadIdx.y;   // 32x8
    for (int r = 0; r < 4; ++r)
        t[ty + 8 * r][tx] = src[(size_t)(y0 + ty + 8 * r) * 2048 + x0 + tx];
    __syncthreads();
    for (int r = 0; r < 4; ++r)
        dst[(size_t)(x0 + ty + 8 * r) * 2048 + y0 + tx] = (__bf16)t[tx][ty + 8 * r];
}

// ---------------- per-head V transpose: qkv[s][4096+h*128+d] -> vtb[h][d][s] ----------------
__global__ __launch_bounds__(256) void v_transpose(const __bf16* __restrict__ qkv,
                                                   __bf16* __restrict__ vtb) {
    __shared__ __bf16 t[32][33];
    int h = blockIdx.z;
    int s0 = blockIdx.x * 32, d0 = blockIdx.y * 32;
    int tx = threadIdx.x, ty = threadIdx.y;   // 32x8
    for (int r = 0; r < 4; ++r)
        t[ty + 8 * r][tx] = qkv[(size_t)(s0 + ty + 8 * r) * 6144 + 4096 + h * 128 + d0 + tx];
    __syncthreads();
    for (int r = 0; r < 4; ++r)
        vtb[(size_t)h * 128 * 4096 + (size_t)(d0 + ty + 8 * r) * 4096 + s0 + tx] = t[tx][ty + 8 * r];
}

// ---------------- fused RMSNorm + RoPE; head-major Q (pre-scaled by log2e/sqrt(128)) and K ----------------
__global__ __launch_bounds__(64) void rmsrope(const __bf16* __restrict__ qkv,
                                              const float* __restrict__ qw,
                                              const float* __restrict__ kw,
                                              const int* __restrict__ pos_ids,
                                              __bf16* __restrict__ qhb,
                                              __bf16* __restrict__ khb) {
    int s = blockIdx.x;
    int slot = blockIdx.y;              // 0..31: 0-15 = q heads, 16-31 = k heads
    int lane = threadIdx.x;             // 0..63, handles dim pair (2*lane, 2*lane+1)
    bool isQ = slot < 16;
    int h = slot & 15;
    size_t base = (size_t)s * 6144 + (isQ ? 0 : 2048) + h * 128 + lane * 2;
    float x0 = (float)qkv[base], x1 = (float)qkv[base + 1];
    float ss = x0 * x0 + x1 * x1;
    for (int m = 1; m < 64; m <<= 1) ss += __shfl_xor(ss, m);
    float rr = rsqrtf(ss * (1.0f / 128.0f) + 1e-6f);
    const float* wp = isQ ? qw : kw;
    float n0 = x0 * rr * wp[lane * 2], n1 = x1 * rr * wp[lane * 2 + 1];
    float freq = powf(10000.0f, -(float)lane * (1.0f / 64.0f));
    float ang = (float)pos_ids[s] * freq;
    float sn, cs;
    sincosf(ang, &sn, &cs);
    float o0 = n0 * cs - n1 * sn;
    float o1 = n0 * sn + n1 * cs;
    // fold (1/sqrt(128)) * log2(e) into Q so scores are in exp2 domain
    if (isQ) { o0 *= 0.12751744416196178f; o1 *= 0.12751744416196178f; }
    __bf16* dst = (isQ ? qhb : khb) + (size_t)h * 4096 * 128 + (size_t)s * 128 + lane * 2;
    dst[0] = (__bf16)o0; dst[1] = (__bf16)o1;
}

// ---------------- generic bf16 MFMA GEMM: C[M,N] = A[M,K] * Bt[N,K]^T ----------------
// 128x128 tile, 4 waves, 4x4 16x16x32 MFMA per wave. global_load_lds width-16 staging (m97).
template <bool F32OUT>
__global__ __launch_bounds__(256) void gemm_bt(const __bf16* __restrict__ A, int lda,
                                               const __bf16* __restrict__ Bt, int ldb,
                                               void* __restrict__ Cout, int ldc, int K) {
    __shared__ __bf16 as[128][32];   // unpadded: required by global_load_lds contiguity
    __shared__ __bf16 bs[128][32];
    const int m0 = blockIdx.x * 128, n0 = blockIdx.y * 128;
    const int t = threadIdx.x;
    const int lane = t & 63, w = t >> 6;
    const int wm = (w >> 1) * 64, wn = (w & 1) * 64;
    const int ln = lane & 15, quad = lane >> 4;
    auto as3 = (AS3 uint32_t*)as;
    auto bs3 = (AS3 uint32_t*)bs;
    f32x4 acc[4][4] = {};
    for (int k0 = 0; k0 < K; k0 += 32) {
        for (int c = 0; c < 2; ++c) {
            int g = c * 256 + t;               // chunk id: 512 chunks of 16B per tile
            int row = g >> 2, kc = g & 3;
            const __bf16* ga = &A[(size_t)(m0 + row) * lda + k0 + kc * 8];
            const __bf16* gb = &Bt[(size_t)(n0 + row) * ldb + k0 + kc * 8];
            __builtin_amdgcn_global_load_lds((const AS1 uint32_t*)ga,
                                             as3 + c * 1024 + w * 256, 16, 0, 0);
            __builtin_amdgcn_global_load_lds((const AS1 uint32_t*)gb,
                                             bs3 + c * 1024 + w * 256, 16, 0, 0);
        }
        __syncthreads();
        bf16x8 af[4], bfr[4];
        for (int i = 0; i < 4; ++i) af[i] = *(const bf16x8*)&as[wm + i * 16 + ln][quad * 8];
        for (int j = 0; j < 4; ++j) bfr[j] = *(const bf16x8*)&bs[wn + j * 16 + ln][quad * 8];
        for (int i = 0; i < 4; ++i)
            for (int j = 0; j < 4; ++j)
                acc[i][j] = MFMA16(af[i], bfr[j], acc[i][j]);
        __syncthreads();
    }
    // C/D layout: col = lane&15, row = quad*4 + r   [m89/m91 verified]
    for (int i = 0; i < 4; ++i)
        for (int j = 0; j < 4; ++j)
            for (int r = 0; r < 4; ++r) {
                int row = m0 + wm + i * 16 + quad * 4 + r;
                int col = n0 + wn + j * 16 + ln;
                if (F32OUT) ((float*)Cout)[(size_t)row * ldc + col] = acc[i][j][r];
                else        ((__bf16*)Cout)[(size_t)row * ldc + col] = (__bf16)acc[i][j][r];
            }
}

// ---------------- flash attention, fixed-max softmax, BM=128 ----------------
// R8 = R7 with ONE change: ps pad-68 replaced by ps[4][32][64] + col XOR-swizzle
// (col ^ ((row&7)<<3), 8-element granularity -> 16B reads stay contiguous).
// Conflict profile ~= stride-68 (writes: 2 writers/word = 2-way free; pf b128 reads:
// 8 distinct chunks per quad = 2-way free) but saves exactly 1024B:
// total LDS 82944 -> 81920 = 80KB -> 2 blocks/CU restored (R7 regression cause:
// 83KB -> 1 block/CU lost the m114 inter-block overlap that absorbs the barrier drain).
// Retained from R7 (proven correct): gload_lds staging (no VGPR transit -> immune to the
// R1-R5 scratch pathology), dbuf + 1 barrier/iter, rule-21 both-sides K/V swizzle, T1 remap.
__global__ __launch_bounds__(256) void flash_attn(const __bf16* __restrict__ Q,
                                                  const __bf16* __restrict__ Kb,
                                                  const __bf16* __restrict__ Vt,
                                                  __bf16* __restrict__ ctx) {
    __shared__ __bf16 kbuf[2][64][128];   // keys x dim, phys chunk = logical ^ (row&7)
    __shared__ __bf16 vbuf[2][128][64];   // dim x keys, same involution
    __shared__ __bf16 ps[4][32][64];      // per-wave P; col ^ ((row&7)<<3) swizzle

    // T1: XCD-contiguous remap (verified R1-R7: FETCH 139MB -> 25MB)
    int bid = blockIdx.x + (int)gridDim.x * blockIdx.y;
    int swz = (bid & 7) * 64 + (bid >> 3);
    const int h  = swz >> 5;
    const int m0 = (swz & 31) * 128;

    const int t = threadIdx.x;
    const int lane = t & 63, w = t >> 6;
    const int ln = lane & 15, quad = lane >> 4;
    const __bf16* Qh = Q + (size_t)h * 4096 * 128;
    const __bf16* Kh = Kb + (size_t)h * 4096 * 128;
    const __bf16* Vh = Vt + (size_t)h * 128 * 4096;

    // per-thread swizzled source chunks (loop-invariant)
    const int kcc = (t & 15) ^ ((t >> 4) & 7);   // K/Q: 16 chunks/row of 16B
    const int vcc = (t & 7) ^ ((t >> 3) & 7);    // V: 8 chunks/row of 16B
    auto kb3 = (AS3 uint32_t*)&kbuf[0][0][0];
    auto vb3 = (AS3 uint32_t*)&vbuf[0][0][0];
    const char* kbase = (const char*)&kbuf[0][0][0];
    const char* vbase = (const char*)&vbuf[0][0][0];

    // ---- stage Q through kbuf[0] (swizzled, regular stores), keep A-frags in registers ----
    bf16x8 qf[2][4];
    for (int half = 0; half < 2; ++half) {
        for (int i = 0; i < 4; ++i) {
            int row = (t >> 4) + i * 16;
            // phys slot (t&15) holds logical chunk kcc = (t&15)^(row&7)
            *(uint4*)&kbuf[0][row][(t & 15) * 8] =
                *(const uint4*)&Qh[(size_t)(m0 + half * 64 + row) * 128 + kcc * 8];
        }
        __syncthreads();
        int r = w * 16 + ln;
        for (int kk = 0; kk < 4; ++kk)
            qf[half][kk] = *(const bf16x8*)(kbase + r * 256 + ((((kk * 4 + quad) ^ (ln & 7)) << 4)));
        __syncthreads();
    }

    // ---- 2-phase pipeline: STAGE issues gload_lds; one barrier per iter ----
    // STAGE(tile -> buf): K 64x128 (4 calls) + V^T 128x64 (4 calls), 16B/lane each
#define STAGE_KV(buf, tile)                                                          \
    for (int i = 0; i < 4; ++i) {                                                    \
        int krow = (t >> 4) + i * 16;                                                \
        __builtin_amdgcn_global_load_lds(                                            \
            (const AS1 uint32_t*)&Kh[(size_t)((tile) * 64 + krow) * 128 + kcc * 8],  \
            kb3 + (buf) * 4096 + (w * 64 + i * 256) * 4, 16, 0, 0);                  \
        int vrow = (t >> 3) + i * 32;                                                \
        __builtin_amdgcn_global_load_lds(                                            \
            (const AS1 uint32_t*)&Vh[(size_t)vrow * 4096 + (tile) * 64 + vcc * 8],   \
            vb3 + (buf) * 4096 + (w * 64 + i * 256) * 4, 16, 0, 0);                  \
    }

    STAGE_KV(0, 0)
    __syncthreads();                  // drains tile-0 loads (compiler vmcnt before barrier)

    f32x4 oacc[2][8] = {};
    float rs[2][4] = {};              // per-lane partial sum of p (no rescale ever needed)
    int cur = 0;

    for (int kb = 0; kb < 64; ++kb) {
        if (kb + 1 < 64) { STAGE_KV(cur ^ 1, kb + 1) }   // async: lands under compute below

        const char* ksb = kbase + cur * 16384;
        const char* vsb = vbase + cur * 16384;

        // S~ = Q*K^T - 16.5 (bias via MFMA C-init); each kf frag reused for both row-tiles
        f32x4 sacc[2][4];
        const f32x4 mC = {-16.5f, -16.5f, -16.5f, -16.5f};
        for (int i = 0; i < 2; ++i)
            for (int j = 0; j < 4; ++j) sacc[i][j] = mC;
        for (int j = 0; j < 4; ++j)
            for (int kk = 0; kk < 4; ++kk) {
                bf16x8 kf = *(const bf16x8*)(ksb + (j * 16 + ln) * 256 +
                                             (((kk * 4 + quad) ^ (ln & 7)) << 4));
                sacc[0][j] = MFMA16(qf[0][kk], kf, sacc[0][j]);
                sacc[1][j] = MFMA16(qf[1][kk], kf, sacc[1][j]);
            }

        // p = exp2(s~); accumulate per-lane partial l; C-layout -> ps (wave-private, no barrier)
        for (int i = 0; i < 2; ++i)
            for (int j = 0; j < 4; ++j)
                for (int r = 0; r < 4; ++r) {
                    float p = EXP2F(sacc[i][j][r]);
                    rs[i][r] += p;
                    int prow = i * 16 + quad * 4 + r;
                    ps[w][prow][(j * 16 + ln) ^ ((prow & 7) << 3)] = (__bf16)p;
                }

        // O += P*V; each vf frag reused for both row-tiles
        bf16x8 pf[2][2];
        for (int i = 0; i < 2; ++i)
            for (int kk = 0; kk < 2; ++kk)
                pf[i][kk] = *(const bf16x8*)&ps[w][i * 16 + ln][(kk * 32 + quad * 8) ^ ((ln & 7) << 3)];
        for (int t8 = 0; t8 < 8; ++t8)
            for (int kk = 0; kk < 2; ++kk) {
                bf16x8 vf = *(const bf16x8*)(vsb + (t8 * 16 + ln) * 128 +
                                             (((kk * 4 + quad) ^ (ln & 7)) << 4));
                oacc[0][t8] = MFMA16(pf[0][kk], vf, oacc[0][t8]);
                oacc[1][t8] = MFMA16(pf[1][kk], vf, oacc[1][t8]);
            }
        __syncthreads();              // everyone done reading buf[cur] AND next tile landed
        cur ^= 1;
    }
#undef STAGE_KV

    // reduce l across the 16 lanes of each quad-row, once
    float inv[2][4];
    for (int i = 0; i < 2; ++i)
        for (int r = 0; r < 4; ++r) {
            float s = rs[i][r];
            for (int msk = 1; msk < 16; msk <<= 1) s += __shfl_xor(s, msk);
            inv[i][r] = 1.0f / s;
        }
    for (int i = 0; i < 2; ++i)
        for (int t8 = 0; t8 < 8; ++t8)
            for (int r = 0; r < 4; ++r) {
                int row = m0 + i * 64 + w * 16 + quad * 4 + r;
                int col = h * 128 + t8 * 16 + ln;
                ctx[(size_t)row * 2048 + col] = (__bf16)(oacc[i][t8][r] * inv[i][r]);
            }
}

// ---------------- launch ----------------
extern "C" void kernel_launch(void* const* d_in, const int* in_sizes, int n_in,
                              void* d_out, int out_size, void* d_ws, size_t ws_size,
                              hipStream_t stream) {
    const float* hs  = (const float*)d_in[0];
    const int*   pos = (const int*)d_in[1];
    const float* wq  = (const float*)d_in[2];
    const float* wk  = (const float*)d_in[3];
    const float* wv  = (const float*)d_in[4];
    const float* wo  = (const float*)d_in[5];
    const float* qw  = (const float*)d_in[6];
    const float* kw  = (const float*)d_in[7];

    char* ws = (char*)d_ws;
    const size_t MB = 1024 * 1024;
    __bf16* xb     = (__bf16*)(ws + 0);
    __bf16* wqkvtb = (__bf16*)(ws + 16 * MB);
    __bf16* qhb    = (__bf16*)(ws + 0);
    __bf16* khb    = (__bf16*)(ws + 16 * MB);
    __bf16* vtb    = (__bf16*)(ws + 32 * MB);
    __bf16* qkvb   = (__bf16*)(ws + 48 * MB);
    __bf16* ctxb   = (__bf16*)(ws + 48 * MB);
    __bf16* wotb   = (__bf16*)(ws + 96 * MB);

    dim3 tb(32, 8);
    convert_f32_bf16<<<8192, 256, 0, stream>>>(hs, xb);
    transpose_conv<<<dim3(64, 64), tb, 0, stream>>>(wq, wqkvtb);
    transpose_conv<<<dim3(64, 64), tb, 0, stream>>>(wk, wqkvtb + (size_t)2048 * 2048);
    transpose_conv<<<dim3(64, 64), tb, 0, stream>>>(wv, wqkvtb + (size_t)2 * 2048 * 2048);
    transpose_conv<<<dim3(64, 64), tb, 0, stream>>>(wo, wotb);

    // QKV projection: [4096,2048] x [2048,6144]
    gemm_bt<false><<<dim3(32, 48), 256, 0, stream>>>(xb, 2048, wqkvtb, 2048, qkvb, 6144, 2048);

    rmsrope<<<dim3(4096, 32), 64, 0, stream>>>(qkvb, qw, kw, pos, qhb, khb);
    v_transpose<<<dim3(128, 4, 16), tb, 0, stream>>>(qkvb, vtb);

    flash_attn<<<dim3(32, 16), 256, 0, stream>>>(qhb, khb, vtb, ctxb);

    // output projection: [4096,2048] x [2048,2048] -> fp32 out
    gemm_bt<true><<<dim3(32, 16), 256, 0, stream>>>(ctxb, 2048, wotb, 2048, d_out, 2048, 2048);
}

// Round 9
// 515.144 us; speedup vs baseline: 1.2842x; 1.0479x over previous
//
#include <hip/hip_runtime.h>

typedef __bf16 bf16x8 __attribute__((ext_vector_type(8)));
typedef __bf16 bf16x4 __attribute__((ext_vector_type(4)));
typedef float  f32x4  __attribute__((ext_vector_type(4)));

#define MFMA16(A, B, C) __builtin_amdgcn_mfma_f32_16x16x32_bf16(A, B, C, 0, 0, 0)
#define AS1 __attribute__((address_space(1)))
#define AS3 __attribute__((address_space(3)))

#if __has_builtin(__builtin_amdgcn_exp2f)
#define EXP2F(x) __builtin_amdgcn_exp2f(x)
#else
#define EXP2F(x) exp2f(x)
#endif

// ---------------- elementwise fp32 -> bf16 ----------------
__global__ __launch_bounds__(256) void convert_f32_bf16(const float* __restrict__ src,
                                                        __bf16* __restrict__ dst) {
    size_t i = ((size_t)blockIdx.x * 256 + threadIdx.x) * 4;
    float4 v = *(const float4*)(src + i);
    bf16x4 o;
    o.x = (__bf16)v.x; o.y = (__bf16)v.y; o.z = (__bf16)v.z; o.w = (__bf16)v.w;
    *(bf16x4*)(dst + i) = o;
}

// ---------------- 2048x2048 fp32 -> bf16 transpose (W -> W^T rows=[n][k]) ----------------
__global__ __launch_bounds__(256) void transpose_conv(const float* __restrict__ src,
                                                      __bf16* __restrict__ dst) {
    __shared__ float t[32][33];
    int x0 = blockIdx.x * 32, y0 = blockIdx.y * 32;
    int tx = threadIdx.x, ty = threadIdx.y;   // 32x8
    for (int r = 0; r < 4; ++r)
        t[ty + 8 * r][tx] = src[(size_t)(y0 + ty + 8 * r) * 2048 + x0 + tx];
    __syncthreads();
    for (int r = 0; r < 4; ++r)
        dst[(size_t)(x0 + ty + 8 * r) * 2048 + y0 + tx] = (__bf16)t[tx][ty + 8 * r];
}

// ---------------- per-head V transpose: qkv[s][4096+h*128+d] -> vtb[h][d][s] ----------------
__global__ __launch_bounds__(256) void v_transpose(const __bf16* __restrict__ qkv,
                                                   __bf16* __restrict__ vtb) {
    __shared__ __bf16 t[32][33];
    int h = blockIdx.z;
    int s0 = blockIdx.x * 32, d0 = blockIdx.y * 32;
    int tx = threadIdx.x, ty = threadIdx.y;   // 32x8
    for (int r = 0; r < 4; ++r)
        t[ty + 8 * r][tx] = qkv[(size_t)(s0 + ty + 8 * r) * 6144 + 4096 + h * 128 + d0 + tx];
    __syncthreads();
    for (int r = 0; r < 4; ++r)
        vtb[(size_t)h * 128 * 4096 + (size_t)(d0 + ty + 8 * r) * 4096 + s0 + tx] = t[tx][ty + 8 * r];
}

// ---------------- fused RMSNorm + RoPE; head-major Q (pre-scaled by log2e/sqrt(128)) and K ----------------
__global__ __launch_bounds__(64) void rmsrope(const __bf16* __restrict__ qkv,
                                              const float* __restrict__ qw,
                                              const float* __restrict__ kw,
                                              const int* __restrict__ pos_ids,
                                              __bf16* __restrict__ qhb,
                                              __bf16* __restrict__ khb) {
    int s = blockIdx.x;
    int slot = blockIdx.y;              // 0..31: 0-15 = q heads, 16-31 = k heads
    int lane = threadIdx.x;             // 0..63, handles dim pair (2*lane, 2*lane+1)
    bool isQ = slot < 16;
    int h = slot & 15;
    size_t base = (size_t)s * 6144 + (isQ ? 0 : 2048) + h * 128 + lane * 2;
    float x0 = (float)qkv[base], x1 = (float)qkv[base + 1];
    float ss = x0 * x0 + x1 * x1;
    for (int m = 1; m < 64; m <<= 1) ss += __shfl_xor(ss, m);
    float rr = rsqrtf(ss * (1.0f / 128.0f) + 1e-6f);
    const float* wp = isQ ? qw : kw;
    float n0 = x0 * rr * wp[lane * 2], n1 = x1 * rr * wp[lane * 2 + 1];
    float freq = powf(10000.0f, -(float)lane * (1.0f / 64.0f));
    float ang = (float)pos_ids[s] * freq;
    float sn, cs;
    sincosf(ang, &sn, &cs);
    float o0 = n0 * cs - n1 * sn;
    float o1 = n0 * sn + n1 * cs;
    // fold (1/sqrt(128)) * log2(e) into Q so scores are in exp2 domain
    if (isQ) { o0 *= 0.12751744416196178f; o1 *= 0.12751744416196178f; }
    __bf16* dst = (isQ ? qhb : khb) + (size_t)h * 4096 * 128 + (size_t)s * 128 + lane * 2;
    dst[0] = (__bf16)o0; dst[1] = (__bf16)o1;
}

// ---------------- generic bf16 MFMA GEMM: C[M,N] = A[M,K] * Bt[N,K]^T ----------------
// R9: 3-deep pipelined K-loop (T3/T4 mechanism on the m97 128x128 tile).
// The 2-barrier m97 loop pays a full vmcnt(0)+lgkmcnt(0) drain at every __syncthreads
// (compiler-inserted) — the guide's measured ~20% structural stall. Here:
//  - as/bs[3]: 48 KB LDS (still 3 blocks/CU — unlike m132's 64 KB regression).
//  - per iter: issue tile kt+2 gload_lds -> asm vmcnt(8) (own tile-kt loads landed;
//    kt+1/kt+2 stay IN FLIGHT, never drains to 0) -> RAW s_barrier (each wave waited
//    on its OWN loads; barrier makes the buffer valid block-wide) -> ds_read+MFMA ->
//    RAW s_barrier (all reads of buf[(kt+2)%3]'s slot done before next iter's issue).
//  - tail: vmcnt(4) then vmcnt(0) for the final two tiles.
// Counted-wait correctness: vmcnt is per-wave; each wave's pre-barrier wait covers its
// own staged chunks, the barrier closes the cross-wave visibility. No __syncthreads in
// the loop, so the compiler emits no drain.
template <bool F32OUT>
__global__ __launch_bounds__(256) void gemm_bt(const __bf16* __restrict__ A, int lda,
                                               const __bf16* __restrict__ Bt, int ldb,
                                               void* __restrict__ Cout, int ldc, int K) {
    __shared__ __bf16 as[3][128][32];   // unpadded: required by global_load_lds contiguity
    __shared__ __bf16 bs[3][128][32];
    const int m0 = blockIdx.x * 128, n0 = blockIdx.y * 128;
    const int t = threadIdx.x;
    const int lane = t & 63, w = t >> 6;
    const int wm = (w >> 1) * 64, wn = (w & 1) * 64;
    const int ln = lane & 15, quad = lane >> 4;
    auto as3 = (AS3 uint32_t*)&as[0][0][0];
    auto bs3 = (AS3 uint32_t*)&bs[0][0][0];
    f32x4 acc[4][4] = {};

    // 4 gload_lds per thread per tile (2 sweeps x {A,B}); 512 chunks of 16B per operand
#define G_STAGE(buf, k0)                                                             \
    for (int c = 0; c < 2; ++c) {                                                    \
        int g = c * 256 + t;                                                         \
        int row = g >> 2, kc = g & 3;                                                \
        __builtin_amdgcn_global_load_lds(                                            \
            (const AS1 uint32_t*)&A[(size_t)(m0 + row) * lda + (k0) + kc * 8],       \
            as3 + (buf) * 2048 + c * 1024 + w * 256, 16, 0, 0);                      \
        __builtin_amdgcn_global_load_lds(                                            \
            (const AS1 uint32_t*)&Bt[(size_t)(n0 + row) * ldb + (k0) + kc * 8],      \
            bs3 + (buf) * 2048 + c * 1024 + w * 256, 16, 0, 0);                      \
    }

    const int nk = K >> 5;            // K-tiles of 32 (nk >= 2 for all our calls)
    G_STAGE(0, 0)
    G_STAGE(1, 32)
    for (int kt = 0; kt < nk; ++kt) {
        const int nxt = kt + 2;
        if (nxt < nk) {
            G_STAGE(nxt % 3, nxt * 32)
            asm volatile("s_waitcnt vmcnt(8)" ::: "memory");   // tile kt landed; 2 tiles in flight
        } else if (nxt == nk) {
            asm volatile("s_waitcnt vmcnt(4)" ::: "memory");   // tile kt landed; kt+1 in flight
        } else {
            asm volatile("s_waitcnt vmcnt(0)" ::: "memory");   // last tile
        }
        __builtin_amdgcn_s_barrier();
        const int b = kt % 3;
        bf16x8 af[4], bfr[4];
        for (int i = 0; i < 4; ++i) af[i] = *(const bf16x8*)&as[b][wm + i * 16 + ln][quad * 8];
        for (int j = 0; j < 4; ++j) bfr[j] = *(const bf16x8*)&bs[b][wn + j * 16 + ln][quad * 8];
        for (int i = 0; i < 4; ++i)
            for (int j = 0; j < 4; ++j)
                acc[i][j] = MFMA16(af[i], bfr[j], acc[i][j]);
        __builtin_amdgcn_s_barrier();   // reads done before anyone re-targets this slot
    }
#undef G_STAGE

    // C/D layout: col = lane&15, row = quad*4 + r   [m89/m91 verified]
    for (int i = 0; i < 4; ++i)
        for (int j = 0; j < 4; ++j)
            for (int r = 0; r < 4; ++r) {
                int row = m0 + wm + i * 16 + quad * 4 + r;
                int col = n0 + wn + j * 16 + ln;
                if (F32OUT) ((float*)Cout)[(size_t)row * ldc + col] = acc[i][j][r];
                else        ((__bf16*)Cout)[(size_t)row * ldc + col] = (__bf16)acc[i][j][r];
            }
}

// ---------------- flash attention, fixed-max softmax, BM=128 (R8 proven, unchanged) ----------------
// Valid because q/k are RMS-normalized: |s*log2e| <= sqrt(128)*log2e = 16.33 < 16.5.
// p = exp2(s~ - 16.5) is exact softmax after final division; no running max/rescale.
// Proven stack: gload_lds staging (immune to the R1-R5 reg-prefetch scratch pathology),
// dbuf + 1 barrier/iter, rule-21 both-sides K/V swizzle, ps XOR-swizzle (80KB = 2 blocks/CU),
// T1 XCD remap (FETCH 139MB -> 25MB). R8: 186us, MfmaUtil 32%, WRITE 16.4MB clean.
__global__ __launch_bounds__(256) void flash_attn(const __bf16* __restrict__ Q,
                                                  const __bf16* __restrict__ Kb,
                                                  const __bf16* __restrict__ Vt,
                                                  __bf16* __restrict__ ctx) {
    __shared__ __bf16 kbuf[2][64][128];   // keys x dim, phys chunk = logical ^ (row&7)
    __shared__ __bf16 vbuf[2][128][64];   // dim x keys, same involution
    __shared__ __bf16 ps[4][32][64];      // per-wave P; col ^ ((row&7)<<3) swizzle

    int bid = blockIdx.x + (int)gridDim.x * blockIdx.y;
    int swz = (bid & 7) * 64 + (bid >> 3);
    const int h  = swz >> 5;
    const int m0 = (swz & 31) * 128;

    const int t = threadIdx.x;
    const int lane = t & 63, w = t >> 6;
    const int ln = lane & 15, quad = lane >> 4;
    const __bf16* Qh = Q + (size_t)h * 4096 * 128;
    const __bf16* Kh = Kb + (size_t)h * 4096 * 128;
    const __bf16* Vh = Vt + (size_t)h * 128 * 4096;

    const int kcc = (t & 15) ^ ((t >> 4) & 7);   // K/Q: 16 chunks/row of 16B
    const int vcc = (t & 7) ^ ((t >> 3) & 7);    // V: 8 chunks/row of 16B
    auto kb3 = (AS3 uint32_t*)&kbuf[0][0][0];
    auto vb3 = (AS3 uint32_t*)&vbuf[0][0][0];
    const char* kbase = (const char*)&kbuf[0][0][0];
    const char* vbase = (const char*)&vbuf[0][0][0];

    // ---- stage Q through kbuf[0] (swizzled, regular stores), keep A-frags in registers ----
    bf16x8 qf[2][4];
    for (int half = 0; half < 2; ++half) {
        for (int i = 0; i < 4; ++i) {
            int row = (t >> 4) + i * 16;
            *(uint4*)&kbuf[0][row][(t & 15) * 8] =
                *(const uint4*)&Qh[(size_t)(m0 + half * 64 + row) * 128 + kcc * 8];
        }
        __syncthreads();
        int r = w * 16 + ln;
        for (int kk = 0; kk < 4; ++kk)
            qf[half][kk] = *(const bf16x8*)(kbase + r * 256 + ((((kk * 4 + quad) ^ (ln & 7)) << 4)));
        __syncthreads();
    }

#define STAGE_KV(buf, tile)                                                          \
    for (int i = 0; i < 4; ++i) {                                                    \
        int krow = (t >> 4) + i * 16;                                                \
        __builtin_amdgcn_global_load_lds(                                            \
            (const AS1 uint32_t*)&Kh[(size_t)((tile) * 64 + krow) * 128 + kcc * 8],  \
            kb3 + (buf) * 4096 + (w * 64 + i * 256) * 4, 16, 0, 0);                  \
        int vrow = (t >> 3) + i * 32;                                                \
        __builtin_amdgcn_global_load_lds(                                            \
            (const AS1 uint32_t*)&Vh[(size_t)vrow * 4096 + (tile) * 64 + vcc * 8],   \
            vb3 + (buf) * 4096 + (w * 64 + i * 256) * 4, 16, 0, 0);                  \
    }

    STAGE_KV(0, 0)
    __syncthreads();

    f32x4 oacc[2][8] = {};
    float rs[2][4] = {};
    int cur = 0;

    for (int kb = 0; kb < 64; ++kb) {
        if (kb + 1 < 64) { STAGE_KV(cur ^ 1, kb + 1) }

        const char* ksb = kbase + cur * 16384;
        const char* vsb = vbase + cur * 16384;

        f32x4 sacc[2][4];
        const f32x4 mC = {-16.5f, -16.5f, -16.5f, -16.5f};
        for (int i = 0; i < 2; ++i)
            for (int j = 0; j < 4; ++j) sacc[i][j] = mC;
        for (int j = 0; j < 4; ++j)
            for (int kk = 0; kk < 4; ++kk) {
                bf16x8 kf = *(const bf16x8*)(ksb + (j * 16 + ln) * 256 +
                                             (((kk * 4 + quad) ^ (ln & 7)) << 4));
                sacc[0][j] = MFMA16(qf[0][kk], kf, sacc[0][j]);
                sacc[1][j] = MFMA16(qf[1][kk], kf, sacc[1][j]);
            }

        for (int i = 0; i < 2; ++i)
            for (int j = 0; j < 4; ++j)
                for (int r = 0; r < 4; ++r) {
                    float p = EXP2F(sacc[i][j][r]);
                    rs[i][r] += p;
                    int prow = i * 16 + quad * 4 + r;
                    ps[w][prow][(j * 16 + ln) ^ ((prow & 7) << 3)] = (__bf16)p;
                }

        bf16x8 pf[2][2];
        for (int i = 0; i < 2; ++i)
            for (int kk = 0; kk < 2; ++kk)
                pf[i][kk] = *(const bf16x8*)&ps[w][i * 16 + ln][(kk * 32 + quad * 8) ^ ((ln & 7) << 3)];
        for (int t8 = 0; t8 < 8; ++t8)
            for (int kk = 0; kk < 2; ++kk) {
                bf16x8 vf = *(const bf16x8*)(vsb + (t8 * 16 + ln) * 128 +
                                             (((kk * 4 + quad) ^ (ln & 7)) << 4));
                oacc[0][t8] = MFMA16(pf[0][kk], vf, oacc[0][t8]);
                oacc[1][t8] = MFMA16(pf[1][kk], vf, oacc[1][t8]);
            }
        __syncthreads();
        cur ^= 1;
    }
#undef STAGE_KV

    float inv[2][4];
    for (int i = 0; i < 2; ++i)
        for (int r = 0; r < 4; ++r) {
            float s = rs[i][r];
            for (int msk = 1; msk < 16; msk <<= 1) s += __shfl_xor(s, msk);
            inv[i][r] = 1.0f / s;
        }
    for (int i = 0; i < 2; ++i)
        for (int t8 = 0; t8 < 8; ++t8)
            for (int r = 0; r < 4; ++r) {
                int row = m0 + i * 64 + w * 16 + quad * 4 + r;
                int col = h * 128 + t8 * 16 + ln;
                ctx[(size_t)row * 2048 + col] = (__bf16)(oacc[i][t8][r] * inv[i][r]);
            }
}

// ---------------- launch ----------------
extern "C" void kernel_launch(void* const* d_in, const int* in_sizes, int n_in,
                              void* d_out, int out_size, void* d_ws, size_t ws_size,
                              hipStream_t stream) {
    const float* hs  = (const float*)d_in[0];
    const int*   pos = (const int*)d_in[1];
    const float* wq  = (const float*)d_in[2];
    const float* wk  = (const float*)d_in[3];
    const float* wv  = (const float*)d_in[4];
    const float* wo  = (const float*)d_in[5];
    const float* qw  = (const float*)d_in[6];
    const float* kw  = (const float*)d_in[7];

    char* ws = (char*)d_ws;
    const size_t MB = 1024 * 1024;
    __bf16* xb     = (__bf16*)(ws + 0);
    __bf16* wqkvtb = (__bf16*)(ws + 16 * MB);
    __bf16* qhb    = (__bf16*)(ws + 0);
    __bf16* khb    = (__bf16*)(ws + 16 * MB);
    __bf16* vtb    = (__bf16*)(ws + 32 * MB);
    __bf16* qkvb   = (__bf16*)(ws + 48 * MB);
    __bf16* ctxb   = (__bf16*)(ws + 48 * MB);
    __bf16* wotb   = (__bf16*)(ws + 96 * MB);

    dim3 tb(32, 8);
    convert_f32_bf16<<<8192, 256, 0, stream>>>(hs, xb);
    transpose_conv<<<dim3(64, 64), tb, 0, stream>>>(wq, wqkvtb);
    transpose_conv<<<dim3(64, 64), tb, 0, stream>>>(wk, wqkvtb + (size_t)2048 * 2048);
    transpose_conv<<<dim3(64, 64), tb, 0, stream>>>(wv, wqkvtb + (size_t)2 * 2048 * 2048);
    transpose_conv<<<dim3(64, 64), tb, 0, stream>>>(wo, wotb);

    // QKV projection: [4096,2048] x [2048,6144]
    gemm_bt<false><<<dim3(32, 48), 256, 0, stream>>>(xb, 2048, wqkvtb, 2048, qkvb, 6144, 2048);

    rmsrope<<<dim3(4096, 32), 64, 0, stream>>>(qkvb, qw, kw, pos, qhb, khb);
    v_transpose<<<dim3(128, 4, 16), tb, 0, stream>>>(qkvb, vtb);

    flash_attn<<<dim3(32, 16), 256, 0, stream>>>(qhb, khb, vtb, ctxb);

    // output projection: [4096,2048] x [2048,2048] -> fp32 out
    gemm_bt<true><<<dim3(32, 16), 256, 0, stream>>>(ctxb, 2048, wotb, 2048, d_out, 2048, 2048);
}

// Round 10
// 494.294 us; speedup vs baseline: 1.3383x; 1.0422x over previous
//
#include <hip/hip_runtime.h>

typedef __bf16 bf16x8 __attribute__((ext_vector_type(8)));
typedef __bf16 bf16x4 __attribute__((ext_vector_type(4)));
typedef float  f32x4  __attribute__((ext_vector_type(4)));

#define MFMA16(A, B, C) __builtin_amdgcn_mfma_f32_16x16x32_bf16(A, B, C, 0, 0, 0)
#define AS1 __attribute__((address_space(1)))
#define AS3 __attribute__((address_space(3)))

#if __has_builtin(__builtin_amdgcn_exp2f)
#define EXP2F(x) __builtin_amdgcn_exp2f(x)
#else
#define EXP2F(x) exp2f(x)
#endif

// ---------------- fused prep: 4x weight transpose (fp32 W -> bf16 W^T) + hidden fp32->bf16 ----------------
// R10: was 5 separate launches; inter-kernel gap ~8-10us each made launch count the 2nd-largest pot.
// z<4: transpose of {wq,wk,wv,wo}; z==4: convert hs. Bodies identical to the R9-proven kernels.
__global__ __launch_bounds__(256) void prep(const float* __restrict__ hs,
                                            const float* __restrict__ wq,
                                            const float* __restrict__ wk,
                                            const float* __restrict__ wv,
                                            const float* __restrict__ wo,
                                            __bf16* __restrict__ xb,
                                            __bf16* __restrict__ wqkvtb,
                                            __bf16* __restrict__ wotb) {
    __shared__ float tile[32][33];
    const int z = blockIdx.z;
    const int tx = threadIdx.x, ty = threadIdx.y;   // 32x8
    if (z == 4) {                                   // convert: 4096 blocks x 2048 floats
        const int t = ty * 32 + tx;
        size_t bid = (size_t)blockIdx.y * 64 + blockIdx.x;
        size_t base = bid * 2048 + t * 4;
        for (int c = 0; c < 2; ++c) {
            float4 v = *(const float4*)(hs + base + c * 1024);
            bf16x4 o;
            o.x = (__bf16)v.x; o.y = (__bf16)v.y; o.z = (__bf16)v.z; o.w = (__bf16)v.w;
            *(bf16x4*)(xb + base + c * 1024) = o;
        }
        return;
    }
    const float* src = (z == 0) ? wq : (z == 1) ? wk : (z == 2) ? wv : wo;
    __bf16* dst = (z < 3) ? (wqkvtb + (size_t)z * 2048 * 2048) : wotb;
    int x0 = blockIdx.x * 32, y0 = blockIdx.y * 32;
    for (int r = 0; r < 4; ++r)
        tile[ty + 8 * r][tx] = src[(size_t)(y0 + ty + 8 * r) * 2048 + x0 + tx];
    __syncthreads();
    for (int r = 0; r < 4; ++r)
        dst[(size_t)(x0 + ty + 8 * r) * 2048 + y0 + tx] = (__bf16)tile[tx][ty + 8 * r];
}

// ---------------- fused rmsrope + per-head V transpose (both consume qkvb) ----------------
// grid (1024, 40), 256 threads. y<32: RMSNorm+RoPE for slot y, 4 tokens/block (one wave each;
// shuffle reduce stays wave-local). y>=32: V transpose (8x1024 = 8192 tile-blocks).
// powf -> exp2f: freq = 2^(-lane * log2(1e4)/64), single v_exp_f32 vs libcall.
__global__ __launch_bounds__(256) void rope_vt(const __bf16* __restrict__ qkv,
                                               const float* __restrict__ qw,
                                               const float* __restrict__ kw,
                                               const int* __restrict__ pos_ids,
                                               __bf16* __restrict__ qhb,
                                               __bf16* __restrict__ khb,
                                               __bf16* __restrict__ vtb) {
    __shared__ __bf16 tile[32][33];
    if (blockIdx.y < 32) {
        int u = threadIdx.x >> 6, lane = threadIdx.x & 63;
        int s = blockIdx.x * 4 + u;
        int slot = blockIdx.y;              // 0-15 = q heads, 16-31 = k heads
        bool isQ = slot < 16;
        int h = slot & 15;
        size_t base = (size_t)s * 6144 + (isQ ? 0 : 2048) + h * 128 + lane * 2;
        float x0 = (float)qkv[base], x1 = (float)qkv[base + 1];
        float ss = x0 * x0 + x1 * x1;
        for (int m = 1; m < 64; m <<= 1) ss += __shfl_xor(ss, m);
        float rr = rsqrtf(ss * (1.0f / 128.0f) + 1e-6f);
        const float* wp = isQ ? qw : kw;
        float n0 = x0 * rr * wp[lane * 2], n1 = x1 * rr * wp[lane * 2 + 1];
        // freq = 10000^(-lane/64) = exp2(-lane * log2(10000)/64)
        float freq = EXP2F(-(float)lane * 0.2076205059004571f);
        float ang = (float)pos_ids[s] * freq;
        float sn, cs;
        sincosf(ang, &sn, &cs);
        float o0 = n0 * cs - n1 * sn;
        float o1 = n0 * sn + n1 * cs;
        // fold (1/sqrt(128)) * log2(e) into Q so scores are in exp2 domain
        if (isQ) { o0 *= 0.12751744416196178f; o1 *= 0.12751744416196178f; }
        __bf16* dst = (isQ ? qhb : khb) + (size_t)h * 4096 * 128 + (size_t)s * 128 + lane * 2;
        dst[0] = (__bf16)o0; dst[1] = (__bf16)o1;
    } else {
        int linear = (blockIdx.y - 32) * 1024 + blockIdx.x;   // [0, 8192)
        int h = linear >> 9, rem = linear & 511;
        int s0 = (rem & 127) * 32, d0 = (rem >> 7) * 32;
        int tx = threadIdx.x & 31, ty = threadIdx.x >> 5;     // 32x8
        for (int r = 0; r < 4; ++r)
            tile[ty + 8 * r][tx] = qkv[(size_t)(s0 + ty + 8 * r) * 6144 + 4096 + h * 128 + d0 + tx];
        __syncthreads();
        for (int r = 0; r < 4; ++r)
            vtb[(size_t)h * 128 * 4096 + (size_t)(d0 + ty + 8 * r) * 4096 + s0 + tx] = tile[tx][ty + 8 * r];
    }
}

// ---------------- generic bf16 MFMA GEMM: C[M,N] = A[M,K] * Bt[N,K]^T ----------------
// R9-proven: 3-deep pipelined K-loop (T3/T4), counted vmcnt (never drains to 0 in steady
// state), raw s_barriers, 48 KB LDS (3 blocks/CU). See R9 notes.
template <bool F32OUT>
__global__ __launch_bounds__(256) void gemm_bt(const __bf16* __restrict__ A, int lda,
                                               const __bf16* __restrict__ Bt, int ldb,
                                               void* __restrict__ Cout, int ldc, int K) {
    __shared__ __bf16 as[3][128][32];   // unpadded: required by global_load_lds contiguity
    __shared__ __bf16 bs[3][128][32];
    const int m0 = blockIdx.x * 128, n0 = blockIdx.y * 128;
    const int t = threadIdx.x;
    const int lane = t & 63, w = t >> 6;
    const int wm = (w >> 1) * 64, wn = (w & 1) * 64;
    const int ln = lane & 15, quad = lane >> 4;
    auto as3 = (AS3 uint32_t*)&as[0][0][0];
    auto bs3 = (AS3 uint32_t*)&bs[0][0][0];
    f32x4 acc[4][4] = {};

#define G_STAGE(buf, k0)                                                             \
    for (int c = 0; c < 2; ++c) {                                                    \
        int g = c * 256 + t;                                                         \
        int row = g >> 2, kc = g & 3;                                                \
        __builtin_amdgcn_global_load_lds(                                            \
            (const AS1 uint32_t*)&A[(size_t)(m0 + row) * lda + (k0) + kc * 8],       \
            as3 + (buf) * 2048 + c * 1024 + w * 256, 16, 0, 0);                      \
        __builtin_amdgcn_global_load_lds(                                            \
            (const AS1 uint32_t*)&Bt[(size_t)(n0 + row) * ldb + (k0) + kc * 8],      \
            bs3 + (buf) * 2048 + c * 1024 + w * 256, 16, 0, 0);                      \
    }

    const int nk = K >> 5;            // K-tiles of 32 (nk >= 2 for all our calls)
    G_STAGE(0, 0)
    G_STAGE(1, 32)
    for (int kt = 0; kt < nk; ++kt) {
        const int nxt = kt + 2;
        if (nxt < nk) {
            G_STAGE(nxt % 3, nxt * 32)
            asm volatile("s_waitcnt vmcnt(8)" ::: "memory");   // tile kt landed; 2 in flight
        } else if (nxt == nk) {
            asm volatile("s_waitcnt vmcnt(4)" ::: "memory");
        } else {
            asm volatile("s_waitcnt vmcnt(0)" ::: "memory");
        }
        __builtin_amdgcn_s_barrier();
        const int b = kt % 3;
        bf16x8 af[4], bfr[4];
        for (int i = 0; i < 4; ++i) af[i] = *(const bf16x8*)&as[b][wm + i * 16 + ln][quad * 8];
        for (int j = 0; j < 4; ++j) bfr[j] = *(const bf16x8*)&bs[b][wn + j * 16 + ln][quad * 8];
        for (int i = 0; i < 4; ++i)
            for (int j = 0; j < 4; ++j)
                acc[i][j] = MFMA16(af[i], bfr[j], acc[i][j]);
        __builtin_amdgcn_s_barrier();   // reads done before anyone re-targets this slot
    }
#undef G_STAGE

    // C/D layout: col = lane&15, row = quad*4 + r   [m89/m91 verified]
    for (int i = 0; i < 4; ++i)
        for (int j = 0; j < 4; ++j)
            for (int r = 0; r < 4; ++r) {
                int row = m0 + wm + i * 16 + quad * 4 + r;
                int col = n0 + wn + j * 16 + ln;
                if (F32OUT) ((float*)Cout)[(size_t)row * ldc + col] = acc[i][j][r];
                else        ((__bf16*)Cout)[(size_t)row * ldc + col] = (__bf16)acc[i][j][r];
            }
}

// ---------------- flash attention, fixed-max softmax, BM=128 (R8/R9 proven, unchanged) ----------------
// Valid because q/k are RMS-normalized: |s*log2e| <= sqrt(128)*log2e = 16.33 < 16.5.
// p = exp2(s~ - 16.5) is exact softmax after final division; no running max/rescale.
// Proven stack: gload_lds staging (immune to the R1-R5 reg-prefetch scratch pathology),
// dbuf + 1 barrier/iter, rule-21 both-sides K/V swizzle, ps XOR-swizzle (80KB = 2 blocks/CU),
// T1 XCD remap (FETCH 139MB -> 25MB). R8/R9: ~187us, MfmaUtil 32%, WRITE 16.4MB clean.
__global__ __launch_bounds__(256) void flash_attn(const __bf16* __restrict__ Q,
                                                  const __bf16* __restrict__ Kb,
                                                  const __bf16* __restrict__ Vt,
                                                  __bf16* __restrict__ ctx) {
    __shared__ __bf16 kbuf[2][64][128];   // keys x dim, phys chunk = logical ^ (row&7)
    __shared__ __bf16 vbuf[2][128][64];   // dim x keys, same involution
    __shared__ __bf16 ps[4][32][64];      // per-wave P; col ^ ((row&7)<<3) swizzle

    int bid = blockIdx.x + (int)gridDim.x * blockIdx.y;
    int swz = (bid & 7) * 64 + (bid >> 3);
    const int h  = swz >> 5;
    const int m0 = (swz & 31) * 128;

    const int t = threadIdx.x;
    const int lane = t & 63, w = t >> 6;
    const int ln = lane & 15, quad = lane >> 4;
    const __bf16* Qh = Q + (size_t)h * 4096 * 128;
    const __bf16* Kh = Kb + (size_t)h * 4096 * 128;
    const __bf16* Vh = Vt + (size_t)h * 128 * 4096;

    const int kcc = (t & 15) ^ ((t >> 4) & 7);   // K/Q: 16 chunks/row of 16B
    const int vcc = (t & 7) ^ ((t >> 3) & 7);    // V: 8 chunks/row of 16B
    auto kb3 = (AS3 uint32_t*)&kbuf[0][0][0];
    auto vb3 = (AS3 uint32_t*)&vbuf[0][0][0];
    const char* kbase = (const char*)&kbuf[0][0][0];
    const char* vbase = (const char*)&vbuf[0][0][0];

    // ---- stage Q through kbuf[0] (swizzled, regular stores), keep A-frags in registers ----
    bf16x8 qf[2][4];
    for (int half = 0; half < 2; ++half) {
        for (int i = 0; i < 4; ++i) {
            int row = (t >> 4) + i * 16;
            *(uint4*)&kbuf[0][row][(t & 15) * 8] =
                *(const uint4*)&Qh[(size_t)(m0 + half * 64 + row) * 128 + kcc * 8];
        }
        __syncthreads();
        int r = w * 16 + ln;
        for (int kk = 0; kk < 4; ++kk)
            qf[half][kk] = *(const bf16x8*)(kbase + r * 256 + ((((kk * 4 + quad) ^ (ln & 7)) << 4)));
        __syncthreads();
    }

#define STAGE_KV(buf, tile)                                                          \
    for (int i = 0; i < 4; ++i) {                                                    \
        int krow = (t >> 4) + i * 16;                                                \
        __builtin_amdgcn_global_load_lds(                                            \
            (const AS1 uint32_t*)&Kh[(size_t)((tile) * 64 + krow) * 128 + kcc * 8],  \
            kb3 + (buf) * 4096 + (w * 64 + i * 256) * 4, 16, 0, 0);                  \
        int vrow = (t >> 3) + i * 32;                                                \
        __builtin_amdgcn_global_load_lds(                                            \
            (const AS1 uint32_t*)&Vh[(size_t)vrow * 4096 + (tile) * 64 + vcc * 8],   \
            vb3 + (buf) * 4096 + (w * 64 + i * 256) * 4, 16, 0, 0);                  \
    }

    STAGE_KV(0, 0)
    __syncthreads();

    f32x4 oacc[2][8] = {};
    float rs[2][4] = {};
    int cur = 0;

    for (int kb = 0; kb < 64; ++kb) {
        if (kb + 1 < 64) { STAGE_KV(cur ^ 1, kb + 1) }

        const char* ksb = kbase + cur * 16384;
        const char* vsb = vbase + cur * 16384;

        f32x4 sacc[2][4];
        const f32x4 mC = {-16.5f, -16.5f, -16.5f, -16.5f};
        for (int i = 0; i < 2; ++i)
            for (int j = 0; j < 4; ++j) sacc[i][j] = mC;
        for (int j = 0; j < 4; ++j)
            for (int kk = 0; kk < 4; ++kk) {
                bf16x8 kf = *(const bf16x8*)(ksb + (j * 16 + ln) * 256 +
                                             (((kk * 4 + quad) ^ (ln & 7)) << 4));
                sacc[0][j] = MFMA16(qf[0][kk], kf, sacc[0][j]);
                sacc[1][j] = MFMA16(qf[1][kk], kf, sacc[1][j]);
            }

        for (int i = 0; i < 2; ++i)
            for (int j = 0; j < 4; ++j)
                for (int r = 0; r < 4; ++r) {
                    float p = EXP2F(sacc[i][j][r]);
                    rs[i][r] += p;
                    int prow = i * 16 + quad * 4 + r;
                    ps[w][prow][(j * 16 + ln) ^ ((prow & 7) << 3)] = (__bf16)p;
                }

        bf16x8 pf[2][2];
        for (int i = 0; i < 2; ++i)
            for (int kk = 0; kk < 2; ++kk)
                pf[i][kk] = *(const bf16x8*)&ps[w][i * 16 + ln][(kk * 32 + quad * 8) ^ ((ln & 7) << 3)];
        for (int t8 = 0; t8 < 8; ++t8)
            for (int kk = 0; kk < 2; ++kk) {
                bf16x8 vf = *(const bf16x8*)(vsb + (t8 * 16 + ln) * 128 +
                                             (((kk * 4 + quad) ^ (ln & 7)) << 4));
                oacc[0][t8] = MFMA16(pf[0][kk], vf, oacc[0][t8]);
                oacc[1][t8] = MFMA16(pf[1][kk], vf, oacc[1][t8]);
            }
        __syncthreads();
        cur ^= 1;
    }
#undef STAGE_KV

    float inv[2][4];
    for (int i = 0; i < 2; ++i)
        for (int r = 0; r < 4; ++r) {
            float s = rs[i][r];
            for (int msk = 1; msk < 16; msk <<= 1) s += __shfl_xor(s, msk);
            inv[i][r] = 1.0f / s;
        }
    for (int i = 0; i < 2; ++i)
        for (int t8 = 0; t8 < 8; ++t8)
            for (int r = 0; r < 4; ++r) {
                int row = m0 + i * 64 + w * 16 + quad * 4 + r;
                int col = h * 128 + t8 * 16 + ln;
                ctx[(size_t)row * 2048 + col] = (__bf16)(oacc[i][t8][r] * inv[i][r]);
            }
}

// ---------------- launch (R10: 5 launches, was 10) ----------------
extern "C" void kernel_launch(void* const* d_in, const int* in_sizes, int n_in,
                              void* d_out, int out_size, void* d_ws, size_t ws_size,
                              hipStream_t stream) {
    const float* hs  = (const float*)d_in[0];
    const int*   pos = (const int*)d_in[1];
    const float* wq  = (const float*)d_in[2];
    const float* wk  = (const float*)d_in[3];
    const float* wv  = (const float*)d_in[4];
    const float* wo  = (const float*)d_in[5];
    const float* qw  = (const float*)d_in[6];
    const float* kw  = (const float*)d_in[7];

    char* ws = (char*)d_ws;
    const size_t MB = 1024 * 1024;
    __bf16* xb     = (__bf16*)(ws + 0);
    __bf16* wqkvtb = (__bf16*)(ws + 16 * MB);
    __bf16* qhb    = (__bf16*)(ws + 0);
    __bf16* khb    = (__bf16*)(ws + 16 * MB);
    __bf16* vtb    = (__bf16*)(ws + 32 * MB);
    __bf16* qkvb   = (__bf16*)(ws + 48 * MB);
    __bf16* ctxb   = (__bf16*)(ws + 48 * MB);
    __bf16* wotb   = (__bf16*)(ws + 96 * MB);

    // prep: z<4 weight transposes, z=4 hidden-state convert
    prep<<<dim3(64, 64, 5), dim3(32, 8), 0, stream>>>(hs, wq, wk, wv, wo, xb, wqkvtb, wotb);

    // QKV projection: [4096,2048] x [2048,6144]
    gemm_bt<false><<<dim3(32, 48), 256, 0, stream>>>(xb, 2048, wqkvtb, 2048, qkvb, 6144, 2048);

    // fused rmsrope (y<32) + per-head V transpose (y>=32)
    rope_vt<<<dim3(1024, 40), 256, 0, stream>>>(qkvb, qw, kw, pos, qhb, khb, vtb);

    flash_attn<<<dim3(32, 16), 256, 0, stream>>>(qhb, khb, vtb, ctxb);

    // output projection: [4096,2048] x [2048,2048] -> fp32 out
    gemm_bt<true><<<dim3(32, 16), 256, 0, stream>>>(ctxb, 2048, wotb, 2048, d_out, 2048, 2048);
}